// Round 8
// baseline (621.468 us; speedup 1.0000x reference)
//
#include <hip/hip_runtime.h>

#define N_NODES 100000
#define N_EDGES 3200000
#define CH 256

#define GRID_C 768       // 3 blocks/CU on 256 CUs -> guaranteed co-resident
#define EPB 2084         // edges per sort tile
#define TILES 1536       // GRID_C*2; 1536*2084 >= 3.2M
#define NB2 25           // bucket = row >> 12
#define BSZ 4096
#define G_AGG 30         // slices per bucket; 25*30=750 jobs <= 768
#define SLICE 52         // ceil(TILES/G_AGG)
#define CHUNK 131        // ceil(N_NODES/GRID_C)

// ---- ws float offsets ----
#define OFF_BAR    0         // 8 ints (barrier slots, zeroed by k_binit)
#define OFF_PTOT   16        // 1536
#define OFF_YUP    1552      // 768*256 = 196608
#define OFF_PRE    198160    // 1536*26 = 39936 ints
#define OFF_Q      238096    // 100000
#define OFF_K      338096    // 100000
#define OFF_PART   438096    // 25*30*4096 = 3072000
#define OFF_EX     3510096   // 1536*2084 = 3201024
#define OFF_ROW    6711120   // 3201024 u16 = 1600512 floats
// end = 8311632 floats ~= 33.2 MB (ws ~410 MB)

struct SMemSort {
    int cnt[4][NB2];
    int bsum[NB2];
    int pref[NB2 + 1];
    float sm[4];
    float lex[EPB];
    unsigned short lrow[EPB];
};
struct SMemAgg {
    float acc[BSZ];
    int segA[SLICE];
    int segB[SLICE];
};
struct SMemPool {
    float awn[CHUNK + 5];
    float sm[4];
    float totsh;
    float4 tmp4[4][64];
};
struct SMemFin {
    float ysh[256];
    float red[256];
};
union SMemU {
    SMemSort s;
    SMemAgg a;
    SMemPool p;
    SMemFin f;
};

__device__ __forceinline__ void gridbar(int* bar, int slot, int nblk) {
    __syncthreads();
    if (threadIdx.x == 0) {
        __threadfence();                       // agent-scope release (L2 wb)
        atomicAdd(&bar[slot], 1);
        while (__hip_atomic_load(&bar[slot], __ATOMIC_RELAXED,
                                 __HIP_MEMORY_SCOPE_AGENT) < nblk)
            __builtin_amdgcn_s_sleep(2);
        __threadfence();                       // acquire (L2 inv)
    }
    __syncthreads();
}

__global__ void k_binit(int* bar) {
    if (threadIdx.x < 8) bar[threadIdx.x] = 0;
}

__global__ __launch_bounds__(256, 3) void k_fused(
        const float* __restrict__ x, const int* __restrict__ ei,
        const float* __restrict__ Wq, const float* __restrict__ bq,
        const float* __restrict__ Wk, const float* __restrict__ bk,
        const float* __restrict__ Wv, const float* __restrict__ bv,
        float* __restrict__ out, float* __restrict__ ws) {
    __shared__ SMemU sm;
    int t = threadIdx.x, blk = blockIdx.x;

    int*            bar     = (int*)ws;
    float*          ptot    = ws + OFF_PTOT;
    float*          yup     = ws + OFF_YUP;
    int*            pre     = (int*)(ws + OFF_PRE);
    float*          q       = ws + OFF_Q;
    float*          k       = ws + OFF_K;
    float*          partial = ws + OFF_PART;
    float*          ex      = ws + OFF_EX;
    unsigned short* row     = (unsigned short*)(ws + OFF_ROW);
    float*          aw_out  = out + CH;

    // ---------------- P1: q/k projections ----------------
    {
        int w = t >> 6, lane = t & 63, g = lane >> 4, seg = lane & 15;
        float4 wq4[4], wk4[4];
        #pragma unroll
        for (int j = 0; j < 4; ++j) {
            wq4[j] = ((const float4*)Wq)[seg + 16 * j];
            wk4[j] = ((const float4*)Wk)[seg + 16 * j];
        }
        float bqs = bq[0], bks = bk[0];
        for (int b0 = blk * 64; b0 < N_NODES; b0 += GRID_C * 64) {
            int base = b0 + w * 16 + g;
            #pragma unroll
            for (int i = 0; i < 4; ++i) {
                int n = base + i * 4;
                if (n < N_NODES) {
                    const float4* xr = (const float4*)(x + (size_t)n * CH);
                    float dq = 0.0f, dk = 0.0f;
                    #pragma unroll
                    for (int j = 0; j < 4; ++j) {
                        float4 xv = xr[seg + 16 * j];
                        dq = fmaf(xv.x, wq4[j].x, fmaf(xv.y, wq4[j].y,
                             fmaf(xv.z, wq4[j].z, fmaf(xv.w, wq4[j].w, dq))));
                        dk = fmaf(xv.x, wk4[j].x, fmaf(xv.y, wk4[j].y,
                             fmaf(xv.z, wk4[j].z, fmaf(xv.w, wk4[j].w, dk))));
                    }
                    dq += __shfl_down(dq, 8); dq += __shfl_down(dq, 4);
                    dq += __shfl_down(dq, 2); dq += __shfl_down(dq, 1);
                    dk += __shfl_down(dk, 8); dk += __shfl_down(dk, 4);
                    dk += __shfl_down(dk, 2); dk += __shfl_down(dk, 1);
                    if (seg == 0) { q[n] = dq + bqs; k[n] = dk + bks; }
                }
            }
        }
    }
    gridbar(bar, 0, GRID_C);

    // ---------------- P2: edge exp + LDS counting sort by bucket ----------------
    for (int tile = blk; tile < TILES; tile += GRID_C) {
        int e0 = tile * EPB;
        int ecnt = min(EPB, N_EDGES - e0);
        int w = t >> 6;
        if (t < 4 * NB2) ((int*)sm.s.cnt)[t] = 0;
        __syncthreads();
        int rr[9]; float ee[9];
        #pragma unroll
        for (int j = 0; j < 9; ++j) {
            int i = j * 256 + t;
            if (i < ecnt) {
                int r = ei[e0 + i], c = ei[N_EDGES + e0 + i];
                float v = q[r] * k[c];
                v = (v >= 0.0f) ? v : 0.2f * v;
                rr[j] = r; ee[j] = __expf(v);
                atomicAdd(&sm.s.cnt[w][r >> 12], 1);
            } else { rr[j] = -1; ee[j] = 0.0f; }
        }
        __syncthreads();
        if (t < NB2) {
            int c0 = sm.s.cnt[0][t], c1 = sm.s.cnt[1][t];
            int c2 = sm.s.cnt[2][t], c3 = sm.s.cnt[3][t];
            sm.s.cnt[0][t] = 0; sm.s.cnt[1][t] = c0;
            sm.s.cnt[2][t] = c0 + c1; sm.s.cnt[3][t] = c0 + c1 + c2;
            sm.s.bsum[t] = c0 + c1 + c2 + c3;
        }
        __syncthreads();
        if (t == 0) {
            int run = 0;
            #pragma unroll
            for (int b = 0; b < NB2; ++b) { sm.s.pref[b] = run; run += sm.s.bsum[b]; }
            sm.s.pref[NB2] = run;
        }
        __syncthreads();
        if (t < 4 * NB2) {
            int ww = t / NB2, b = t - ww * NB2;
            sm.s.cnt[ww][b] += sm.s.pref[b];
        }
        if (t < NB2 + 1) pre[tile * 26 + t] = sm.s.pref[t];
        __syncthreads();
        #pragma unroll
        for (int j = 0; j < 9; ++j) {
            if (rr[j] >= 0) {
                int b = rr[j] >> 12;
                int p = atomicAdd(&sm.s.cnt[w][b], 1);
                sm.s.lex[p] = ee[j];
                sm.s.lrow[p] = (unsigned short)(rr[j] & (BSZ - 1));
            }
        }
        float s = 0.0f;
        #pragma unroll
        for (int j = 0; j < 9; ++j) s += ee[j];
        #pragma unroll
        for (int off = 32; off; off >>= 1) s += __shfl_down(s, off);
        if ((t & 63) == 0) sm.s.sm[w] = s;
        __syncthreads();
        if (t == 0) ptot[tile] = sm.s.sm[0] + sm.s.sm[1] + sm.s.sm[2] + sm.s.sm[3];
        size_t gb = (size_t)tile * EPB;
        for (int i = t; i < ecnt; i += 256) ex[gb + i] = sm.s.lex[i];
        unsigned* ro = (unsigned*)(row + gb);
        const unsigned* lr = (const unsigned*)sm.s.lrow;
        int words = (ecnt + 1) >> 1;
        for (int i = t; i < words; i += 256) ro[i] = lr[i];
    }
    gridbar(bar, 1, GRID_C);

    // ---------------- P3: per-(bucket,slice) LDS aggregation ----------------
    if (blk < NB2 * G_AGG) {
        int b = blk / G_AGG, g = blk % G_AGG;
        for (int i = t; i < BSZ; i += 256) sm.a.acc[i] = 0.0f;
        int sb0 = g * SLICE, sb1 = min(sb0 + SLICE, TILES);
        int nseg = sb1 - sb0;
        if (t < nseg) {
            sm.a.segA[t] = pre[(sb0 + t) * 26 + b];
            sm.a.segB[t] = pre[(sb0 + t) * 26 + b + 1];
        }
        __syncthreads();
        int hw = t >> 5, lane = t & 31;
        for (int sI = hw; sI < nseg; sI += 8) {
            size_t gb = (size_t)(sb0 + sI) * EPB;
            int s0 = sm.a.segA[sI], s1 = sm.a.segB[sI];
            for (int i = s0 + lane; i < s1; i += 32)
                atomicAdd(&sm.a.acc[row[gb + i]], ex[gb + i]);
        }
        __syncthreads();
        float* dst = partial + ((size_t)b * G_AGG + g) * BSZ;
        for (int i = t; i < BSZ; i += 256) dst[i] = sm.a.acc[i];
    }
    gridbar(bar, 2, GRID_C);

    // ---------------- P4: fold partials -> normalized weights; weighted pool ----------------
    {
        float ts = 0.0f;
        for (int i = t; i < TILES; i += 256) ts += ptot[i];
        #pragma unroll
        for (int off = 32; off; off >>= 1) ts += __shfl_down(ts, off);
        if ((t & 63) == 0) sm.p.sm[t >> 6] = ts;
        __syncthreads();
        if (t == 0) sm.p.totsh = sm.p.sm[0] + sm.p.sm[1] + sm.p.sm[2] + sm.p.sm[3];
        __syncthreads();
        float inv = 1.0f / sm.p.totsh;
        int n0 = blk * CHUNK;
        int cnt = min(CHUNK, N_NODES - n0);   // may be <= 0 for tail blocks
        if (t < cnt) {
            int n = n0 + t, bb = n >> 12, off = n & (BSZ - 1);
            const float* p = partial + (size_t)bb * G_AGG * BSZ + off;
            float ssum = 0.0f;
            #pragma unroll 10
            for (int g = 0; g < G_AGG; ++g) ssum += p[(size_t)g * BSZ];
            float an = ssum * inv;
            sm.p.awn[t] = an;
            aw_out[n] = an;
        }
        __syncthreads();
        int s4 = t >> 6, g4 = t & 63;
        const float4* X4 = (const float4*)x;
        float4 acc = make_float4(0.f, 0.f, 0.f, 0.f);
        for (int i0 = 0; i0 < cnt; i0 += 8) {
            int i1 = i0 + s4, i2 = i0 + 4 + s4;
            if (i1 < cnt) {
                float a0 = sm.p.awn[i1];
                float4 x0 = X4[(size_t)(n0 + i1) * 64 + g4];
                acc.x = fmaf(a0, x0.x, acc.x); acc.y = fmaf(a0, x0.y, acc.y);
                acc.z = fmaf(a0, x0.z, acc.z); acc.w = fmaf(a0, x0.w, acc.w);
            }
            if (i2 < cnt) {
                float a1 = sm.p.awn[i2];
                float4 x1 = X4[(size_t)(n0 + i2) * 64 + g4];
                acc.x = fmaf(a1, x1.x, acc.x); acc.y = fmaf(a1, x1.y, acc.y);
                acc.z = fmaf(a1, x1.z, acc.z); acc.w = fmaf(a1, x1.w, acc.w);
            }
        }
        sm.p.tmp4[s4][g4] = acc;
        __syncthreads();
        const float* tmp = (const float*)sm.p.tmp4;
        float sum = tmp[0 * 256 + t] + tmp[1 * 256 + t] + tmp[2 * 256 + t] + tmp[3 * 256 + t];
        yup[(size_t)blk * 256 + t] = sum;
    }
    gridbar(bar, 3, GRID_C);

    // ---------------- P5: out = y @ Wv + bv (y already normalized) ----------------
    if (blk < 8) {
        float yv = 0.0f;
        #pragma unroll 8
        for (int r = 0; r < GRID_C; ++r) yv += yup[(size_t)r * 256 + t];
        sm.f.ysh[t] = yv;
        __syncthreads();
        int c = blk * 32 + (t & 31), rg = t >> 5;
        float acc = 0.0f;
        #pragma unroll
        for (int j = 0; j < 32; ++j) {
            int kk = rg * 32 + j;
            acc = fmaf(sm.f.ysh[kk], Wv[(size_t)kk * CH + c], acc);
        }
        sm.f.red[t] = acc;
        __syncthreads();
        if (t < 32) {
            float sv = 0.0f;
            #pragma unroll
            for (int j = 0; j < 8; ++j) sv += sm.f.red[j * 32 + t];
            out[blk * 32 + t] = sv + bv[blk * 32 + t];
        }
    }
}

extern "C" void kernel_launch(void* const* d_in, const int* in_sizes, int n_in,
                              void* d_out, int out_size, void* d_ws, size_t ws_size,
                              hipStream_t stream) {
    const float* x  = (const float*)d_in[0];
    const int*   ei = (const int*)d_in[1];
    const float* Wq = (const float*)d_in[2];
    const float* bq = (const float*)d_in[3];
    const float* Wk = (const float*)d_in[4];
    const float* bk = (const float*)d_in[5];
    const float* Wv = (const float*)d_in[6];
    const float* bv = (const float*)d_in[7];
    float* out = (float*)d_out;
    float* ws  = (float*)d_ws;

    hipLaunchKernelGGL(k_binit, dim3(1), dim3(64), 0, stream, (int*)ws);
    hipLaunchKernelGGL(k_fused, dim3(GRID_C), dim3(256), 0, stream,
                       x, ei, Wq, bq, Wk, bk, Wv, bv, out, ws);
}